// Round 1
// baseline (345.601 us; speedup 1.0000x reference)
//
#include <hip/hip_runtime.h>
#include <hip/hip_bf16.h>
#include <cstdint>

// ProbSparse attention (Informer). B=4, L=2048, H=8, D=64, sample_k=u=40.
#define BB 4
#define LL 2048
#define HH 8
#define DD 64
#define SK 40
#define UU 40
#define LDK 68   // LDS row pitch (floats) for K/V tiles: 68 ≡ 4 mod 32 banks

// ---------------------------------------------------------------------------
// Kernel 1: M[b,h,q] = max_s(Q_q · K_idx[q,s]) - mean_s(Q_q · K_idx[q,s])
// thread-per-query; Q row in registers; K rows gathered (L2-resident).
// ---------------------------------------------------------------------------
__global__ __launch_bounds__(256) void k_sample_score(
    const float* __restrict__ Q, const float* __restrict__ K,
    const int* __restrict__ idxs, float* __restrict__ M) {
  int g = blockIdx.x * 256 + threadIdx.x;      // (b*H+h)*L + q
  int q = g & (LL - 1);
  int bh = g >> 11;
  int b = bh >> 3, h = bh & 7;

  const float4* qv = reinterpret_cast<const float4*>(Q + ((size_t)((b * LL + q) * HH + h)) * DD);
  float4 qr[16];
#pragma unroll
  for (int i = 0; i < 16; i++) qr[i] = qv[i];

  float mx = -1e30f, sm = 0.f;
  for (int s = 0; s < SK; s++) {
    int ks = idxs[q * SK + s];
    const float4* kv = reinterpret_cast<const float4*>(K + ((size_t)((b * LL + ks) * HH + h)) * DD);
    float dot = 0.f;
#pragma unroll
    for (int i = 0; i < 16; i++) {
      float4 kk = kv[i];
      dot += qr[i].x * kk.x + qr[i].y * kk.y + qr[i].z * kk.z + qr[i].w * kk.w;
    }
    mx = fmaxf(mx, dot);
    sm += dot;
  }
  M[g] = mx - sm * (1.0f / SK);
}

// ---------------------------------------------------------------------------
// Kernel 2: top-40 indices of M[b,h,:] (lowest-index tie break, like top_k)
// ---------------------------------------------------------------------------
__global__ __launch_bounds__(256) void k_topk(const float* __restrict__ M,
                                              int* __restrict__ Mtop) {
  int bh = blockIdx.x;
  __shared__ float vals[LL];
  __shared__ float rv[256];
  __shared__ int ri[256];
  int t = threadIdx.x;
  for (int i = t; i < LL; i += 256) vals[i] = M[bh * LL + i];
  __syncthreads();
  for (int it = 0; it < UU; it++) {
    float bv = -1e38f;
    int bi = 0;
    for (int i = t; i < LL; i += 256) {
      float v = vals[i];
      if (v > bv) { bv = v; bi = i; }        // ascending scan keeps lowest idx on ties
    }
    rv[t] = bv; ri[t] = bi;
    __syncthreads();
    for (int sft = 128; sft > 0; sft >>= 1) {
      if (t < sft) {
        float ov = rv[t + sft]; int oi = ri[t + sft];
        if (ov > rv[t] || (ov == rv[t] && oi < ri[t])) { rv[t] = ov; ri[t] = oi; }
      }
      __syncthreads();
    }
    if (t == 0) {
      Mtop[bh * UU + it] = ri[0];
      vals[ri[0]] = -1e38f;
    }
    __syncthreads();
  }
}

// ---------------------------------------------------------------------------
// Kernel 3a: per-(b,h) 64-row chunk sums of V (32 chunks)
// ---------------------------------------------------------------------------
__global__ __launch_bounds__(64) void k_chunksum(const float* __restrict__ V,
                                                 float* __restrict__ CS) {
  int blk = blockIdx.x;             // bh*32 + c
  int c = blk & 31, bh = blk >> 5;
  int b = bh >> 3, h = bh & 7;
  int d = threadIdx.x;
  const float* p = V + ((size_t)((b * LL + c * 64) * HH + h)) * DD + d;
  float s = 0.f;
#pragma unroll
  for (int r = 0; r < 64; r++) s += p[(size_t)r * HH * DD];
  CS[blk * 64 + d] = s;
}

// ---------------------------------------------------------------------------
// Kernel 3b: cumsum write: offset from preceding chunk sums + local prefix
// ---------------------------------------------------------------------------
__global__ __launch_bounds__(64) void k_cumsum(const float* __restrict__ V,
                                               const float* __restrict__ CS,
                                               float* __restrict__ Out) {
  int blk = blockIdx.x;
  int c = blk & 31, bh = blk >> 5;
  int b = bh >> 3, h = bh & 7;
  int d = threadIdx.x;
  float run = 0.f;
  for (int cc = 0; cc < c; cc++) run += CS[(bh * 32 + cc) * 64 + d];
  const float* p = V + ((size_t)((b * LL + c * 64) * HH + h)) * DD + d;
  float* o = Out + ((size_t)((b * LL + c * 64) * HH + h)) * DD + d;
  float v[64];
#pragma unroll
  for (int r = 0; r < 64; r++) v[r] = p[(size_t)r * HH * DD];
#pragma unroll
  for (int r = 0; r < 64; r++) {
    run += v[r];
    o[(size_t)r * HH * DD] = run;
  }
}

// ---------------------------------------------------------------------------
// Kernel 4: for each (b,h,u): causal softmax(Q_idx·K^T/8)·V over keys<=idx,
// overwrite Out row idx. Flash-style online softmax, 64-key LDS chunks.
// Lane layout for QK: lane = kk(16 keys) + 16*g(4 d-groups of 16).
// ---------------------------------------------------------------------------
__global__ __launch_bounds__(256) void k_attn(
    const float* __restrict__ Q, const float* __restrict__ K,
    const float* __restrict__ V, const int* __restrict__ Mtop,
    float* __restrict__ Out) {
  int blk = blockIdx.x;            // bh*UU + u
  int u = blk % UU;
  int bh = blk / UU;
  int b = bh >> 3, h = bh & 7;
  int idx = Mtop[bh * UU + u];

  int t = threadIdx.x;
  int w = t >> 6, lane = t & 63;
  int kk = lane & 15, gg = lane >> 4;

  __shared__ float Kt[64 * LDK];
  __shared__ float Vt[64 * LDK];
  __shared__ float qs[64];

  const float* qp = Q + ((size_t)((b * LL + idx) * HH + h)) * DD;
  if (t < 64) qs[t] = qp[t] * 0.125f;   // 1/sqrt(64)
  __syncthreads();

  float qr[16];
#pragma unroll
  for (int j = 0; j < 16; j++) qr[j] = qs[gg * 16 + j];

  float m = -1e30f, l = 0.f, acc = 0.f;   // acc: lane = d
  int nk = idx + 1;
  int nch = (nk + 63) >> 6;

  for (int ch = 0; ch < nch; ch++) {
    __syncthreads();   // protect Kt/Vt from previous iteration readers
    const float4* kg = reinterpret_cast<const float4*>(K + ((size_t)((b * LL + ch * 64) * HH + h)) * DD);
    const float4* vg = reinterpret_cast<const float4*>(V + ((size_t)((b * LL + ch * 64) * HH + h)) * DD);
#pragma unroll
    for (int i = 0; i < 4; i++) {
      int f = t + i * 256;          // 0..1023 float4 slots
      int r = f >> 4, col = f & 15;
      float4 kv4 = kg[(size_t)r * (HH * DD / 4) + col];
      float4 vv4 = vg[(size_t)r * (HH * DD / 4) + col];
      *reinterpret_cast<float4*>(&Kt[r * LDK + col * 4]) = kv4;
      *reinterpret_cast<float4*>(&Vt[r * LDK + col * 4]) = vv4;
    }
    __syncthreads();

    int row = w * 16 + kk;
    int key = ch * 64 + row;
    float dp = 0.f;
#pragma unroll
    for (int j = 0; j < 4; j++) {
      float4 kv4 = *reinterpret_cast<const float4*>(&Kt[row * LDK + gg * 16 + j * 4]);
      dp += qr[j * 4 + 0] * kv4.x + qr[j * 4 + 1] * kv4.y +
            qr[j * 4 + 2] * kv4.z + qr[j * 4 + 3] * kv4.w;
    }
    dp += __shfl_xor(dp, 16);
    dp += __shfl_xor(dp, 32);       // full dot at all lanes sharing kk
    bool valid = (key <= idx);
    float s = valid ? dp : -1e30f;
    float cm = s;
    cm = fmaxf(cm, __shfl_xor(cm, 1));
    cm = fmaxf(cm, __shfl_xor(cm, 2));
    cm = fmaxf(cm, __shfl_xor(cm, 4));
    cm = fmaxf(cm, __shfl_xor(cm, 8));
    float mn = fmaxf(m, cm);
    float f_ = __expf(m - mn);
    float p = valid ? __expf(s - mn) : 0.f;
    float ps = p;
    ps += __shfl_xor(ps, 1);
    ps += __shfl_xor(ps, 2);
    ps += __shfl_xor(ps, 4);
    ps += __shfl_xor(ps, 8);
    l = l * f_ + ps;
    m = mn;
    acc *= f_;
#pragma unroll
    for (int k2 = 0; k2 < 16; k2++) {
      float pk = __shfl(p, k2);     // lane k2 (gg=0) holds p for key k2
      acc += pk * Vt[(w * 16 + k2) * LDK + lane];
    }
  }

  // merge the 4 waves' partial (m, l, acc)
  __syncthreads();
  float* mw = Kt;          // reuse LDS as scratch
  float* lw = Kt + 8;
  float* aw = Vt;          // 4 x 64
  if (lane == 0) { mw[w] = m; lw[w] = l; }
  aw[w * 64 + lane] = acc;
  __syncthreads();
  if (w == 0) {
    float M0 = fmaxf(fmaxf(mw[0], mw[1]), fmaxf(mw[2], mw[3]));
    float Lt = 0.f, A = 0.f;
#pragma unroll
    for (int i = 0; i < 4; i++) {
      float e = __expf(mw[i] - M0);
      Lt += lw[i] * e;
      A += aw[i * 64 + lane] * e;
    }
    Out[((size_t)((b * LL + idx) * HH + h)) * DD + lane] = A / Lt;
  }
}

// ---------------------------------------------------------------------------
extern "C" void kernel_launch(void* const* d_in, const int* in_sizes, int n_in,
                              void* d_out, int out_size, void* d_ws, size_t ws_size,
                              hipStream_t stream) {
  const float* Q = (const float*)d_in[0];
  const float* K = (const float*)d_in[1];
  const float* V = (const float*)d_in[2];
  const int* IS = (const int*)d_in[3];
  // d_in[4] (attn_mask) unused by the reference.
  float* Out = (float*)d_out;

  float* M = (float*)d_ws;                 // 65536 floats
  float* CS = M + BB * HH * LL;            // 65536 floats (32 chunks x 64 d per bh)
  int* Mtop = (int*)(CS + BB * HH * 32 * DD);  // 1280 ints

  k_sample_score<<<BB * HH * LL / 256, 256, 0, stream>>>(Q, K, IS, M);
  k_topk<<<BB * HH, 256, 0, stream>>>(M, Mtop);
  k_chunksum<<<BB * HH * 32, 64, 0, stream>>>(V, CS);
  k_cumsum<<<BB * HH * 32, 64, 0, stream>>>(V, CS, Out);
  k_attn<<<BB * HH * UU, 256, 0, stream>>>(Q, K, V, Mtop, Out);
}

// Round 2
// 265.748 us; speedup vs baseline: 1.3005x; 1.3005x over previous
//
#include <hip/hip_runtime.h>
#include <hip/hip_bf16.h>
#include <cstdint>

// ProbSparse attention (Informer). B=4, L=2048, H=8, D=64, sample_k=u=40.
#define BB 4
#define LL 2048
#define HH 8
#define DD 64
#define SK 40
#define UU 40
#define LDK 68   // LDS row pitch (floats) for K/V tiles: 68 ≡ 4 mod 32 banks

// ---------------------------------------------------------------------------
// Kernel 1: M[b,h,q] = max_s(Q_q · K_idx[q,s]) - mean_s(Q_q · K_idx[q,s])
// 256 thr = 64 queries x 4 d-parts. Grid 1024 with XCD swizzle: each XCD
// owns 4 (b,h) slices (2 MB of K -> L2-resident gathers).
// ---------------------------------------------------------------------------
__global__ __launch_bounds__(256) void k_sample_score(
    const float* __restrict__ Q, const float* __restrict__ K,
    const int* __restrict__ idxs, float* __restrict__ M) {
  int j = blockIdx.x;                 // 0..1023
  int xcd = j & 7, kk = j >> 3;       // kk 0..127
  int bh = (xcd << 2) | (kk >> 5);    // 4 bh per XCD
  int qc = kk & 31;                   // 32 q-chunks of 64
  int b = bh >> 3, h = bh & 7;
  int t = threadIdx.x;
  int ql = t >> 2, dp = t & 3;        // 64 queries x 4 d-parts
  int q0 = qc * 64;
  int q = q0 + ql;

  // sample indices, transposed in LDS: sidx[s*64 + ql]  (bank-conflict-free)
  __shared__ int sidx[SK * 64];
  for (int i = t; i < SK * 64; i += 256)
    sidx[i] = idxs[(q0 + (i & 63)) * SK + (i >> 6)];
  __syncthreads();

  const float4* qv = reinterpret_cast<const float4*>(
      Q + ((size_t)((b * LL + q) * HH + h)) * DD + dp * 16);
  float4 qr[4];
#pragma unroll
  for (int i = 0; i < 4; i++) qr[i] = qv[i];

  const float* kb = K + (size_t)b * (LL * HH * DD) + h * DD + dp * 16;
  float mx = -1e30f, sm = 0.f;
#pragma unroll 4
  for (int s = 0; s < SK; s++) {
    int ks = sidx[s * 64 + ql];
    const float4* kv = reinterpret_cast<const float4*>(kb + (size_t)ks * (HH * DD));
    float dot = 0.f;
#pragma unroll
    for (int i = 0; i < 4; i++) {
      float4 c = kv[i];
      dot += qr[i].x * c.x + qr[i].y * c.y + qr[i].z * c.z + qr[i].w * c.w;
    }
    dot += __shfl_xor(dot, 1);
    dot += __shfl_xor(dot, 2);        // full dot on all 4 d-part lanes
    mx = fmaxf(mx, dot);
    sm += dot;
  }
  if (dp == 0) M[bh * LL + q] = mx - sm * (1.0f / SK);
}

// ---------------------------------------------------------------------------
// Kernel 2: top-40 of M[b,h,:]. One wave; packed u64 keys (ordered-float,
// ~idx) so max-key == (max val, lowest idx) -- matches lax.top_k ties.
// ---------------------------------------------------------------------------
__global__ __launch_bounds__(64) void k_topk(const float* __restrict__ M,
                                             int* __restrict__ Mtop) {
  int bh = blockIdx.x;
  __shared__ unsigned long long keys[LL];
  int l = threadIdx.x;
  for (int tt = 0; tt < LL / 64; tt++) {
    int e = tt * 64 + l;
    unsigned u = __float_as_uint(M[bh * LL + e]);
    u = (u & 0x80000000u) ? ~u : (u | 0x80000000u);   // order-preserving map
    keys[e] = ((unsigned long long)u << 32) | (unsigned)(~e);
  }
  __syncthreads();
  for (int it = 0; it < UU; it++) {
    unsigned long long best = 0ull;
    for (int tt = 0; tt < LL / 64; tt++) {
      unsigned long long k2 = keys[tt * 64 + l];
      best = k2 > best ? k2 : best;
    }
#pragma unroll
    for (int s = 1; s < 64; s <<= 1) {
      unsigned long long o = __shfl_xor(best, s);
      best = o > best ? o : best;
    }
    int bi = (int)(~(unsigned)best) & (LL - 1);
    if (l == 0) {
      Mtop[bh * UU + it] = bi;
      keys[bi] = 0ull;
    }
    __syncthreads();
  }
}

// ---------------------------------------------------------------------------
// Kernel 3a: per-(b,h) 64-row chunk sums of V (32 chunks)
// ---------------------------------------------------------------------------
__global__ __launch_bounds__(64) void k_chunksum(const float* __restrict__ V,
                                                 float* __restrict__ CS) {
  int blk = blockIdx.x;             // bh*32 + c
  int c = blk & 31, bh = blk >> 5;
  int b = bh >> 3, h = bh & 7;
  int d = threadIdx.x;
  const float* p = V + ((size_t)((b * LL + c * 64) * HH + h)) * DD + d;
  float s = 0.f;
#pragma unroll
  for (int r = 0; r < 64; r++) s += p[(size_t)r * HH * DD];
  CS[blk * 64 + d] = s;
}

// ---------------------------------------------------------------------------
// Kernel 3b: cumsum write: offset from preceding chunk sums + local prefix
// ---------------------------------------------------------------------------
__global__ __launch_bounds__(64) void k_cumsum(const float* __restrict__ V,
                                               const float* __restrict__ CS,
                                               float* __restrict__ Out) {
  int blk = blockIdx.x;
  int c = blk & 31, bh = blk >> 5;
  int b = bh >> 3, h = bh & 7;
  int d = threadIdx.x;
  float run = 0.f;
  for (int cc = 0; cc < c; cc++) run += CS[(bh * 32 + cc) * 64 + d];
  const float* p = V + ((size_t)((b * LL + c * 64) * HH + h)) * DD + d;
  float* o = Out + ((size_t)((b * LL + c * 64) * HH + h)) * DD + d;
  float v[64];
#pragma unroll
  for (int r = 0; r < 64; r++) v[r] = p[(size_t)r * HH * DD];
#pragma unroll
  for (int r = 0; r < 64; r++) {
    run += v[r];
    o[(size_t)r * HH * DD] = run;
  }
}

// ---------------------------------------------------------------------------
// Kernel 4: for each (b,h,u): causal softmax(Q_idx·K^T/8)·V over keys<=idx,
// overwrite Out row idx. Flash-style online softmax, 64-key LDS chunks.
// XCD swizzle: 4 bh x 40 u per XCD -> K/V slice L2-resident per XCD.
// ---------------------------------------------------------------------------
__global__ __launch_bounds__(256) void k_attn(
    const float* __restrict__ Q, const float* __restrict__ K,
    const float* __restrict__ V, const int* __restrict__ Mtop,
    float* __restrict__ Out) {
  int j = blockIdx.x;                 // 0..1279
  int xcd = j & 7, slot = j >> 3;     // slot 0..159
  int bh = (xcd << 2) | (slot / 40);
  int u = slot % 40;
  int b = bh >> 3, h = bh & 7;
  int idx = Mtop[bh * UU + u];

  int t = threadIdx.x;
  int w = t >> 6, lane = t & 63;
  int kk = lane & 15, gg = lane >> 4;

  __shared__ float Kt[64 * LDK];
  __shared__ float Vt[64 * LDK];
  __shared__ float qs[64];

  const float* qp = Q + ((size_t)((b * LL + idx) * HH + h)) * DD;
  if (t < 64) qs[t] = qp[t] * 0.125f;   // 1/sqrt(64)
  __syncthreads();

  float qr[16];
#pragma unroll
  for (int jj = 0; jj < 16; jj++) qr[jj] = qs[gg * 16 + jj];

  float m = -1e30f, l = 0.f, acc = 0.f;   // acc: lane = d
  int nk = idx + 1;
  int nch = (nk + 63) >> 6;

  for (int ch = 0; ch < nch; ch++) {
    __syncthreads();   // protect Kt/Vt from previous iteration readers
    const float4* kg = reinterpret_cast<const float4*>(K + ((size_t)((b * LL + ch * 64) * HH + h)) * DD);
    const float4* vg = reinterpret_cast<const float4*>(V + ((size_t)((b * LL + ch * 64) * HH + h)) * DD);
#pragma unroll
    for (int i = 0; i < 4; i++) {
      int f = t + i * 256;          // 0..1023 float4 slots
      int r = f >> 4, col = f & 15;
      float4 kv4 = kg[(size_t)r * (HH * DD / 4) + col];
      float4 vv4 = vg[(size_t)r * (HH * DD / 4) + col];
      *reinterpret_cast<float4*>(&Kt[r * LDK + col * 4]) = kv4;
      *reinterpret_cast<float4*>(&Vt[r * LDK + col * 4]) = vv4;
    }
    __syncthreads();

    int row = w * 16 + kk;
    int key = ch * 64 + row;
    float dp = 0.f;
#pragma unroll
    for (int jj = 0; jj < 4; jj++) {
      float4 kv4 = *reinterpret_cast<const float4*>(&Kt[row * LDK + gg * 16 + jj * 4]);
      dp += qr[jj * 4 + 0] * kv4.x + qr[jj * 4 + 1] * kv4.y +
            qr[jj * 4 + 2] * kv4.z + qr[jj * 4 + 3] * kv4.w;
    }
    dp += __shfl_xor(dp, 16);
    dp += __shfl_xor(dp, 32);       // full dot at all lanes sharing kk
    bool valid = (key <= idx);
    float s = valid ? dp : -1e30f;
    float cm = s;
    cm = fmaxf(cm, __shfl_xor(cm, 1));
    cm = fmaxf(cm, __shfl_xor(cm, 2));
    cm = fmaxf(cm, __shfl_xor(cm, 4));
    cm = fmaxf(cm, __shfl_xor(cm, 8));
    float mn = fmaxf(m, cm);
    float f_ = __expf(m - mn);
    float p = valid ? __expf(s - mn) : 0.f;
    float ps = p;
    ps += __shfl_xor(ps, 1);
    ps += __shfl_xor(ps, 2);
    ps += __shfl_xor(ps, 4);
    ps += __shfl_xor(ps, 8);
    l = l * f_ + ps;
    m = mn;
    acc *= f_;
#pragma unroll
    for (int k2 = 0; k2 < 16; k2++) {
      float pk = __shfl(p, k2);     // lane k2 (gg=0) holds p for key k2
      acc += pk * Vt[(w * 16 + k2) * LDK + lane];
    }
  }

  // merge the 4 waves' partial (m, l, acc)
  __syncthreads();
  float* mw = Kt;          // reuse LDS as scratch
  float* lw = Kt + 8;
  float* aw = Vt;          // 4 x 64
  if (lane == 0) { mw[w] = m; lw[w] = l; }
  aw[w * 64 + lane] = acc;
  __syncthreads();
  if (w == 0) {
    float M0 = fmaxf(fmaxf(mw[0], mw[1]), fmaxf(mw[2], mw[3]));
    float Lt = 0.f, A = 0.f;
#pragma unroll
    for (int i = 0; i < 4; i++) {
      float e = __expf(mw[i] - M0);
      Lt += lw[i] * e;
      A += aw[i * 64 + lane] * e;
    }
    Out[((size_t)((b * LL + idx) * HH + h)) * DD + lane] = A / Lt;
  }
}

// ---------------------------------------------------------------------------
extern "C" void kernel_launch(void* const* d_in, const int* in_sizes, int n_in,
                              void* d_out, int out_size, void* d_ws, size_t ws_size,
                              hipStream_t stream) {
  const float* Q = (const float*)d_in[0];
  const float* K = (const float*)d_in[1];
  const float* V = (const float*)d_in[2];
  const int* IS = (const int*)d_in[3];
  // d_in[4] (attn_mask) unused by the reference.
  float* Out = (float*)d_out;

  float* M = (float*)d_ws;                 // 65536 floats
  float* CS = M + BB * HH * LL;            // 65536 floats
  int* Mtop = (int*)(CS + BB * HH * 32 * DD);  // 1280 ints

  k_sample_score<<<1024, 256, 0, stream>>>(Q, K, IS, M);
  k_topk<<<BB * HH, 64, 0, stream>>>(M, Mtop);
  k_chunksum<<<BB * HH * 32, 64, 0, stream>>>(V, CS);
  k_cumsum<<<BB * HH * 32, 64, 0, stream>>>(V, CS, Out);
  k_attn<<<BB * HH * UU, 256, 0, stream>>>(Q, K, V, Mtop, Out);
}

// Round 4
// 238.034 us; speedup vs baseline: 1.4519x; 1.1164x over previous
//
#include <hip/hip_runtime.h>
#include <hip/hip_bf16.h>
#include <cstdint>

// ProbSparse attention (Informer). B=4, L=2048, H=8, D=64, sample_k=u=40.
#define BB 4
#define LL 2048
#define HH 8
#define DD 64
#define SK 40
#define UU 40
#define LDK 68    // LDS row pitch (floats): 68 ≡ 4 mod 32 banks
#define NSEG 32   // key segments of 64 for two-phase attention

// ---------------------------------------------------------------------------
// Kernel 1: M[b,h,q] = max_s(Q_q · K_idx[q,s]) - mean_s(Q_q · K_idx[q,s])
// 256 thr = 64 queries x 4 d-parts. XCD swizzle: 4 (b,h) slices per XCD.
// ---------------------------------------------------------------------------
__global__ __launch_bounds__(256) void k_sample_score(
    const float* __restrict__ Q, const float* __restrict__ K,
    const int* __restrict__ idxs, float* __restrict__ M) {
  int j = blockIdx.x;                 // 0..1023
  int xcd = j & 7, kk = j >> 3;       // kk 0..127
  int bh = (xcd << 2) | (kk >> 5);    // 4 bh per XCD
  int qc = kk & 31;                   // 32 q-chunks of 64
  int b = bh >> 3, h = bh & 7;
  int t = threadIdx.x;
  int ql = t >> 2, dp = t & 3;        // 64 queries x 4 d-parts
  int q0 = qc * 64;
  int q = q0 + ql;

  __shared__ int sidx[SK * 64];       // transposed sample indices
  for (int i = t; i < SK * 64; i += 256)
    sidx[i] = idxs[(q0 + (i & 63)) * SK + (i >> 6)];
  __syncthreads();

  const float4* qv = reinterpret_cast<const float4*>(
      Q + ((size_t)((b * LL + q) * HH + h)) * DD + dp * 16);
  float4 qr[4];
#pragma unroll
  for (int i = 0; i < 4; i++) qr[i] = qv[i];

  const float* kb = K + (size_t)b * (LL * HH * DD) + h * DD + dp * 16;
  float mx = -1e30f, sm = 0.f;
#pragma unroll 4
  for (int s = 0; s < SK; s++) {
    int ks = sidx[s * 64 + ql];
    const float4* kv = reinterpret_cast<const float4*>(kb + (size_t)ks * (HH * DD));
    float dot = 0.f;
#pragma unroll
    for (int i = 0; i < 4; i++) {
      float4 c = kv[i];
      dot += qr[i].x * c.x + qr[i].y * c.y + qr[i].z * c.z + qr[i].w * c.w;
    }
    dot += __shfl_xor(dot, 1);
    dot += __shfl_xor(dot, 2);
    mx = fmaxf(mx, dot);
    sm += dot;
  }
  if (dp == 0) M[bh * LL + q] = mx - sm * (1.0f / SK);
}

// ---------------------------------------------------------------------------
// Kernel 2: top-40 of M[b,h,:]. 256 thr; packed u64 keys (ordered-float,
// ~idx) so max-key == (max val, lowest idx) -- matches lax.top_k ties.
// ---------------------------------------------------------------------------
__global__ __launch_bounds__(256) void k_topk(const float* __restrict__ M,
                                              int* __restrict__ Mtop) {
  int bh = blockIdx.x;
  __shared__ unsigned long long keys[LL];
  __shared__ unsigned long long wbest[4];
  int t = threadIdx.x;
  int w = t >> 6, lane = t & 63;
  for (int i = t; i < LL; i += 256) {
    unsigned u = __float_as_uint(M[bh * LL + i]);
    u = (u & 0x80000000u) ? ~u : (u | 0x80000000u);
    keys[i] = ((unsigned long long)u << 32) | (unsigned)(~i);
  }
  __syncthreads();
  for (int it = 0; it < UU; it++) {
    unsigned long long best = 0ull;
#pragma unroll
    for (int tt = 0; tt < 8; tt++) {
      unsigned long long k2 = keys[tt * 256 + t];
      best = k2 > best ? k2 : best;
    }
#pragma unroll
    for (int s = 1; s < 64; s <<= 1) {
      unsigned long long o = __shfl_xor(best, s);
      best = o > best ? o : best;
    }
    if (lane == 0) wbest[w] = best;
    __syncthreads();
    if (t == 0) {
      unsigned long long b0 = wbest[0];
      b0 = wbest[1] > b0 ? wbest[1] : b0;
      b0 = wbest[2] > b0 ? wbest[2] : b0;
      b0 = wbest[3] > b0 ? wbest[3] : b0;
      int bi = (int)(~(unsigned)b0) & (LL - 1);
      Mtop[bh * UU + it] = bi;
      keys[bi] = 0ull;
    }
    __syncthreads();
  }
}

// ---------------------------------------------------------------------------
// Kernel 3a: per-(b,h) 64-row chunk sums of V (32 chunks)
// ---------------------------------------------------------------------------
__global__ __launch_bounds__(64) void k_chunksum(const float* __restrict__ V,
                                                 float* __restrict__ CS) {
  int blk = blockIdx.x;
  int c = blk & 31, bh = blk >> 5;
  int b = bh >> 3, h = bh & 7;
  int d = threadIdx.x;
  const float* p = V + ((size_t)((b * LL + c * 64) * HH + h)) * DD + d;
  float s = 0.f;
#pragma unroll
  for (int r = 0; r < 64; r++) s += p[(size_t)r * HH * DD];
  CS[blk * 64 + d] = s;
}

// ---------------------------------------------------------------------------
// Kernel 3b: cumsum write: offset from preceding chunk sums + local prefix
// ---------------------------------------------------------------------------
__global__ __launch_bounds__(64) void k_cumsum(const float* __restrict__ V,
                                               const float* __restrict__ CS,
                                               float* __restrict__ Out) {
  int blk = blockIdx.x;
  int c = blk & 31, bh = blk >> 5;
  int b = bh >> 3, h = bh & 7;
  int d = threadIdx.x;
  float run = 0.f;
  for (int cc = 0; cc < c; cc++) run += CS[(bh * 32 + cc) * 64 + d];
  const float* p = V + ((size_t)((b * LL + c * 64) * HH + h)) * DD + d;
  float* o = Out + ((size_t)((b * LL + c * 64) * HH + h)) * DD + d;
  float v[64];
#pragma unroll
  for (int r = 0; r < 64; r++) v[r] = p[(size_t)r * HH * DD];
#pragma unroll
  for (int r = 0; r < 64; r++) {
    run += v[r];
    o[(size_t)r * HH * DD] = run;
  }
}

// ---------------------------------------------------------------------------
// Kernel 4a: partial attention. Block = (bh, seg of 64 keys). Stage K/V
// segment once; each wave serves 10 of the 40 queries. Partial (m,l,acc[64])
// per (bh,u,seg) -> Part. Segments with seg*64 > idx are skipped (merge
// never reads them).
// ---------------------------------------------------------------------------
__global__ __launch_bounds__(256) void k_attn_part(
    const float* __restrict__ Q, const float* __restrict__ K,
    const float* __restrict__ V, const int* __restrict__ Mtop,
    float* __restrict__ Part) {
  int j = blockIdx.x;                  // 0..1023
  int xcd = j & 7, r_ = j >> 3;        // r_ 0..127
  int bh = (xcd << 2) | (r_ & 3);      // 4 bh per XCD
  int seg = r_ >> 2;                   // 0..31
  int b = bh >> 3, h = bh & 7;
  int s0 = seg * 64;

  int t = threadIdx.x;
  int w = t >> 6, lane = t & 63;
  int kk = lane & 15, gg = lane >> 4;

  __shared__ float Kt[64 * LDK];
  __shared__ float Vt[64 * LDK];
  __shared__ int midx[UU];

  if (t < UU) midx[t] = Mtop[bh * UU + t];

  const float4* kg = reinterpret_cast<const float4*>(
      K + ((size_t)((b * LL + s0) * HH + h)) * DD);
  const float4* vg = reinterpret_cast<const float4*>(
      V + ((size_t)((b * LL + s0) * HH + h)) * DD);
#pragma unroll
  for (int i = 0; i < 4; i++) {
    int f = t + i * 256;               // 0..1023 float4 slots
    int r = f >> 4, col = f & 15;
    float4 kv4 = kg[(size_t)r * (HH * DD / 4) + col];
    float4 vv4 = vg[(size_t)r * (HH * DD / 4) + col];
    *reinterpret_cast<float4*>(&Kt[r * LDK + col * 4]) = kv4;
    *reinterpret_cast<float4*>(&Vt[r * LDK + col * 4]) = vv4;
  }
  __syncthreads();

  for (int uu = 0; uu < 10; uu++) {
    int u = w + uu * 4;
    int idx = midx[u];
    if (idx < s0) continue;            // wave-uniform skip
    int kend = idx - s0;               // local last valid key (may exceed 63)
    if (kend > 63) kend = 63;

    const float4* qv = reinterpret_cast<const float4*>(
        Q + ((size_t)((b * LL + idx) * HH + h)) * DD + gg * 16);
    float4 qr0 = qv[0], qr1 = qv[1], qr2 = qv[2], qr3 = qv[3];

    float m = -1e30f, l = 0.f, acc = 0.f;
#pragma unroll
    for (int ks = 0; ks < 4; ks++) {
      if (ks * 16 > kend) break;       // uniform
      int row = ks * 16 + kk;
      float dp = 0.f;
      const float4* kr = reinterpret_cast<const float4*>(&Kt[row * LDK + gg * 16]);
      float4 c0 = kr[0], c1 = kr[1], c2 = kr[2], c3 = kr[3];
      dp += qr0.x * c0.x + qr0.y * c0.y + qr0.z * c0.z + qr0.w * c0.w;
      dp += qr1.x * c1.x + qr1.y * c1.y + qr1.z * c1.z + qr1.w * c1.w;
      dp += qr2.x * c2.x + qr2.y * c2.y + qr2.z * c2.z + qr2.w * c2.w;
      dp += qr3.x * c3.x + qr3.y * c3.y + qr3.z * c3.z + qr3.w * c3.w;
      dp += __shfl_xor(dp, 16);
      dp += __shfl_xor(dp, 32);        // full dot everywhere
      bool valid = (row <= kend);
      float s = valid ? dp * 0.125f : -1e30f;
      float cm = s;
      cm = fmaxf(cm, __shfl_xor(cm, 1));
      cm = fmaxf(cm, __shfl_xor(cm, 2));
      cm = fmaxf(cm, __shfl_xor(cm, 4));
      cm = fmaxf(cm, __shfl_xor(cm, 8));
      float mn = fmaxf(m, cm);
      float f_ = __expf(m - mn);
      float p = valid ? __expf(s - mn) : 0.f;
      float ps = p;
      ps += __shfl_xor(ps, 1);
      ps += __shfl_xor(ps, 2);
      ps += __shfl_xor(ps, 4);
      ps += __shfl_xor(ps, 8);
      l = l * f_ + ps;
      m = mn;
      acc *= f_;
#pragma unroll
      for (int k2 = 0; k2 < 16; k2++) {
        float pk = __shfl(p, k2);      // lane k2 holds p for key ks*16+k2
        acc += pk * Vt[(ks * 16 + k2) * LDK + lane];
      }
    }

    float* pb = Part + ((size_t)(bh * UU + u) * NSEG + seg) * 66;
    pb[2 + lane] = acc;                // lane = d
    if (lane == 0) { pb[0] = m; pb[1] = l; }
  }
}

// ---------------------------------------------------------------------------
// Kernel 4b: merge <=32 segment partials per (bh,u), overwrite Out row idx.
// ---------------------------------------------------------------------------
__global__ __launch_bounds__(64) void k_attn_merge(
    const int* __restrict__ Mtop, const float* __restrict__ Part,
    float* __restrict__ Out) {
  int blk = blockIdx.x;                // 0..1279
  int bh = blk / UU, u = blk % UU;
  int b = bh >> 3, h = bh & 7;
  int lane = threadIdx.x;
  int idx = Mtop[bh * UU + u];
  int nseg = (idx >> 6) + 1;

  const float* base = Part + (size_t)(bh * UU + u) * NSEG * 66;
  float M0 = -1e30f;
  for (int s = 0; s < nseg; s++) M0 = fmaxf(M0, base[s * 66]);
  float A = 0.f, Lt = 0.f;
  for (int s = 0; s < nseg; s++) {
    float ms = base[s * 66], ls = base[s * 66 + 1];
    float e = __expf(ms - M0);
    Lt += ls * e;
    A += base[s * 66 + 2 + lane] * e;
  }
  Out[((size_t)((b * LL + idx) * HH + h)) * DD + lane] = A / Lt;
}

// ---------------------------------------------------------------------------
// Fallback fused attention (r1 version) if workspace is too small.
// ---------------------------------------------------------------------------
__global__ __launch_bounds__(256) void k_attn_fused(
    const float* __restrict__ Q, const float* __restrict__ K,
    const float* __restrict__ V, const int* __restrict__ Mtop,
    float* __restrict__ Out) {
  int j = blockIdx.x;
  int xcd = j & 7, slot = j >> 3;
  int bh = (xcd << 2) | (slot / 40);
  int u = slot % 40;
  int b = bh >> 3, h = bh & 7;
  int idx = Mtop[bh * UU + u];

  int t = threadIdx.x;
  int w = t >> 6, lane = t & 63;
  int kk = lane & 15, gg = lane >> 4;

  __shared__ float Kt[64 * LDK];
  __shared__ float Vt[64 * LDK];
  __shared__ float qs[64];

  const float* qp = Q + ((size_t)((b * LL + idx) * HH + h)) * DD;
  if (t < 64) qs[t] = qp[t] * 0.125f;
  __syncthreads();

  float qr[16];
#pragma unroll
  for (int jj = 0; jj < 16; jj++) qr[jj] = qs[gg * 16 + jj];

  float m = -1e30f, l = 0.f, acc = 0.f;
  int nch = (idx + 64) >> 6;

  for (int ch = 0; ch < nch; ch++) {
    __syncthreads();
    const float4* kg = reinterpret_cast<const float4*>(K + ((size_t)((b * LL + ch * 64) * HH + h)) * DD);
    const float4* vg = reinterpret_cast<const float4*>(V + ((size_t)((b * LL + ch * 64) * HH + h)) * DD);
#pragma unroll
    for (int i = 0; i < 4; i++) {
      int f = t + i * 256;
      int r = f >> 4, col = f & 15;
      float4 kv4 = kg[(size_t)r * (HH * DD / 4) + col];
      float4 vv4 = vg[(size_t)r * (HH * DD / 4) + col];
      *reinterpret_cast<float4*>(&Kt[r * LDK + col * 4]) = kv4;
      *reinterpret_cast<float4*>(&Vt[r * LDK + col * 4]) = vv4;
    }
    __syncthreads();

    int row = w * 16 + kk;
    int key = ch * 64 + row;
    float dp = 0.f;
#pragma unroll
    for (int jj = 0; jj < 4; jj++) {
      float4 kv4 = *reinterpret_cast<const float4*>(&Kt[row * LDK + gg * 16 + jj * 4]);
      dp += qr[jj * 4 + 0] * kv4.x + qr[jj * 4 + 1] * kv4.y +
            qr[jj * 4 + 2] * kv4.z + qr[jj * 4 + 3] * kv4.w;
    }
    dp += __shfl_xor(dp, 16);
    dp += __shfl_xor(dp, 32);
    bool valid = (key <= idx);
    float s = valid ? dp : -1e30f;
    float cm = s;
    cm = fmaxf(cm, __shfl_xor(cm, 1));
    cm = fmaxf(cm, __shfl_xor(cm, 2));
    cm = fmaxf(cm, __shfl_xor(cm, 4));
    cm = fmaxf(cm, __shfl_xor(cm, 8));
    float mn = fmaxf(m, cm);
    float f_ = __expf(m - mn);
    float p = valid ? __expf(s - mn) : 0.f;
    float ps = p;
    ps += __shfl_xor(ps, 1);
    ps += __shfl_xor(ps, 2);
    ps += __shfl_xor(ps, 4);
    ps += __shfl_xor(ps, 8);
    l = l * f_ + ps;
    m = mn;
    acc *= f_;
#pragma unroll
    for (int k2 = 0; k2 < 16; k2++) {
      float pk = __shfl(p, k2);
      acc += pk * Vt[(w * 16 + k2) * LDK + lane];
    }
  }

  __syncthreads();
  float* mw = Kt;
  float* lw = Kt + 8;
  float* aw = Vt;
  if (lane == 0) { mw[w] = m; lw[w] = l; }
  aw[w * 64 + lane] = acc;
  __syncthreads();
  if (w == 0) {
    float M0 = fmaxf(fmaxf(mw[0], mw[1]), fmaxf(mw[2], mw[3]));
    float Lt = 0.f, A = 0.f;
#pragma unroll
    for (int i = 0; i < 4; i++) {
      float e = __expf(mw[i] - M0);
      Lt += lw[i] * e;
      A += aw[i * 64 + lane] * e;
    }
    Out[((size_t)((b * LL + idx) * HH + h)) * DD + lane] = A / Lt;
  }
}

// ---------------------------------------------------------------------------
extern "C" void kernel_launch(void* const* d_in, const int* in_sizes, int n_in,
                              void* d_out, int out_size, void* d_ws, size_t ws_size,
                              hipStream_t stream) {
  const float* Q = (const float*)d_in[0];
  const float* K = (const float*)d_in[1];
  const float* V = (const float*)d_in[2];
  const int* IS = (const int*)d_in[3];
  float* Out = (float*)d_out;

  float* M = (float*)d_ws;                        // 65536 f
  float* CS = M + BB * HH * LL;                   // 65536 f
  int* Mtop = (int*)(CS + BB * HH * 32 * DD);     // 1280 i
  float* Part = (float*)(Mtop + BB * HH * UU);    // 1280*32*66 f = 10.8 MB
  size_t need = (size_t)(BB * HH * LL + BB * HH * 32 * DD) * 4 +
                (size_t)(BB * HH * UU) * 4 +
                (size_t)(BB * HH * UU) * NSEG * 66 * 4;

  k_sample_score<<<1024, 256, 0, stream>>>(Q, K, IS, M);
  k_topk<<<BB * HH, 256, 0, stream>>>(M, Mtop);
  k_chunksum<<<BB * HH * 32, 64, 0, stream>>>(V, CS);
  k_cumsum<<<BB * HH * 32, 64, 0, stream>>>(V, CS, Out);
  if (ws_size >= need) {
    k_attn_part<<<1024, 256, 0, stream>>>(Q, K, V, Mtop, Part);
    k_attn_merge<<<BB * HH * UU, 64, 0, stream>>>(Mtop, Part, Out);
  } else {
    k_attn_fused<<<BB * HH * UU, 256, 0, stream>>>(Q, K, V, Mtop, Out);
  }
}